// Round 3
// baseline (46.233 us; speedup 1.0000x reference)
//
#include <hip/hip_runtime.h>

// ParticleI2cCell: pairwise Gaussian loglik (P x P, D=4) + two row-LSEs.
// smoothed[i] = log(sum_j e_ij*exp(w_j)) - log(sum_j e_ij*exp(lw_j))
// e_ij = exp(m_i . s_j - ||s_j||^2/2)   [exp(-||m_i||^2/2) cancels in the
// log-ratio and is dropped; terms bounded by exp(||m||^2/2) ~ e^10, safe].

typedef float v2f __attribute__((ext_vector_type(2)));

constexpr float LOG2E = 1.4426950408889634f;
constexpr float LN2   = 0.6931471805599453f;

__device__ __forceinline__ v2f splat2(float x) { v2f r; r[0] = x; r[1] = x; return r; }
__device__ __forceinline__ v2f pkfma(v2f a, v2f b, v2f c) {
    return __builtin_elementwise_fma(a, b, c);   // -> v_pk_fma_f32 on gfx90a+
}

// ---------------- precompute: j-table [P][8] AoS + means SoA [4][P] --------
__global__ __launch_bounds__(256) void precompute_kernel(
    const float* __restrict__ particles,
    const float* __restrict__ samples,
    const float* __restrict__ weights,
    const float* __restrict__ log_weights,
    const float* __restrict__ A,
    const float* __restrict__ B,
    const float* __restrict__ log_sigma,
    float* __restrict__ jdata,   // [P][8]: {LOG2E*s0..s3, K*||s||^2, e^lw, e^w, 0}
    float* __restrict__ msoa,    // [4][P] scaled means
    int P)
{
    int i = blockIdx.x * blockDim.x + threadIdx.x;
    if (i >= P) return;

    const float K = -0.5f * LOG2E;

    float inv_s[4];
#pragma unroll
    for (int k = 0; k < 4; ++k)
        inv_s[k] = __builtin_amdgcn_exp2f(-log_sigma[k] * LOG2E);

    float4 sv = reinterpret_cast<const float4*>(samples)[i];
    float s0 = sv.x * inv_s[0], s1 = sv.y * inv_s[1];
    float s2 = sv.z * inv_s[2], s3 = sv.w * inv_s[3];
    float sn = s0*s0 + s1*s1 + s2*s2 + s3*s3;

    float4* jd = reinterpret_cast<float4*>(jdata + (size_t)i * 8);
    jd[0] = make_float4(LOG2E*s0, LOG2E*s1, LOG2E*s2, LOG2E*s3);
    jd[1] = make_float4(K * sn,
                        __builtin_amdgcn_exp2f(log_weights[i] * LOG2E),
                        __builtin_amdgcn_exp2f(weights[i] * LOG2E),
                        0.f);

    const float2* p2 = reinterpret_cast<const float2*>(particles) + (size_t)i * 3;
    float2 x01 = p2[0], x23 = p2[1], u01 = p2[2];
    float x[4] = {x01.x, x01.y, x23.x, x23.y};
    float u[2] = {u01.x, u01.y};
#pragma unroll
    for (int k = 0; k < 4; ++k) {
        float mean =       A[k*4+0] * x[0];
        mean = fmaf(A[k*4+1], x[1], mean);
        mean = fmaf(A[k*4+2], x[2], mean);
        mean = fmaf(A[k*4+3], x[3], mean);
        mean = fmaf(B[k*2+0], u[0], mean);
        mean = fmaf(B[k*2+1], u[1], mean);
        msoa[(size_t)k * P + i] = mean * inv_s[k];
    }
}

// ---------------- pair kernel: R2 packed row-pairs per thread --------------
// grid = (NJ, P/(2*R2*BLOCK)). 4 instrs/pair: 3 pk_fma + 1 exp2.
template <int R2, int BLOCK, int JCHUNK>
__global__ __launch_bounds__(BLOCK) void pair_kernel(
    const float* __restrict__ jdata,
    const float* __restrict__ msoa,
    float* __restrict__ part1,        // [NJ][P]
    float* __restrict__ part2,        // [NJ][P]
    int P)
{
    const int tid = threadIdx.x;
    const int jc  = blockIdx.x;
    const int rowBase = blockIdx.y * (BLOCK * 2 * R2);

    __shared__ __align__(16) float4 jds[JCHUNK * 2];
    if (tid < JCHUNK) {
        const float4* src = reinterpret_cast<const float4*>(jdata) +
                            (size_t)(jc * JCHUNK + tid) * 2;
        jds[tid * 2]     = src[0];
        jds[tid * 2 + 1] = src[1];
    }

    v2f m0[R2], m1[R2], m2[R2], m3[R2], a1[R2], a2[R2];
#pragma unroll
    for (int p = 0; p < R2; ++p) {
        int r0 = rowBase + 2 * tid + p * (2 * BLOCK);
        m0[p] = *reinterpret_cast<const v2f*>(msoa + 0 * (size_t)P + r0);
        m1[p] = *reinterpret_cast<const v2f*>(msoa + 1 * (size_t)P + r0);
        m2[p] = *reinterpret_cast<const v2f*>(msoa + 2 * (size_t)P + r0);
        m3[p] = *reinterpret_cast<const v2f*>(msoa + 3 * (size_t)P + r0);
        a1[p] = splat2(0.f);
        a2[p] = splat2(0.f);
    }

    __syncthreads();

    // register-prefetched j-walk: LDS latency overlaps compute of current j
    float4 av = jds[0], bv = jds[1];
#pragma unroll 4
    for (int jj = 0; jj < JCHUNK; ++jj) {
        float4 avn, bvn;
        if (jj + 1 < JCHUNK) { avn = jds[2*jj + 2]; bvn = jds[2*jj + 3]; }
        v2f va0 = splat2(av.x), va1 = splat2(av.y);
        v2f va2 = splat2(av.z), va3 = splat2(av.w);
        v2f vc  = splat2(bv.x), velw = splat2(bv.y), vew = splat2(bv.z);
#pragma unroll
        for (int p = 0; p < R2; ++p) {
            v2f t = pkfma(m0[p], va0, vc);
            t = pkfma(m1[p], va1, t);
            t = pkfma(m2[p], va2, t);
            t = pkfma(m3[p], va3, t);
            v2f e;
            e[0] = __builtin_amdgcn_exp2f(t[0]);
            e[1] = __builtin_amdgcn_exp2f(t[1]);
            a1[p] = pkfma(e, velw, a1[p]);
            a2[p] = pkfma(e, vew,  a2[p]);
        }
        av = avn; bv = bvn;
    }

#pragma unroll
    for (int p = 0; p < R2; ++p) {
        int r0 = rowBase + 2 * tid + p * (2 * BLOCK);
        *reinterpret_cast<v2f*>(part1 + (size_t)jc * P + r0) = a1[p];
        *reinterpret_cast<v2f*>(part2 + (size_t)jc * P + r0) = a2[p];
    }
}

// ---------------- reduce: fixed-order over NJ partials, log-ratio ----------
__global__ __launch_bounds__(256) void reduce_kernel(
    const float* __restrict__ part1,
    const float* __restrict__ part2,
    float* __restrict__ out, int P, int NJ)
{
    const int rl = threadIdx.x & 63;
    const int sl = threadIdx.x >> 6;          // 0..3
    const int row = blockIdx.x * 64 + rl;

    float s1 = 0.f, s2 = 0.f;
    for (int nj = sl; nj < NJ; nj += 4) {
        s1 += part1[(size_t)nj * P + row];
        s2 += part2[(size_t)nj * P + row];
    }
    __shared__ float l1[4][64], l2[4][64];
    l1[sl][rl] = s1; l2[sl][rl] = s2;
    __syncthreads();
    if (sl == 0) {
        float t1 = ((l1[0][rl] + l1[1][rl]) + l1[2][rl]) + l1[3][rl];
        float t2 = ((l2[0][rl] + l2[1][rl]) + l2[2][rl]) + l2[3][rl];
        out[row] = (__builtin_amdgcn_logf(t2) - __builtin_amdgcn_logf(t1)) * LN2;
    }
}

extern "C" void kernel_launch(void* const* d_in, const int* in_sizes, int n_in,
                              void* d_out, int out_size, void* d_ws, size_t ws_size,
                              hipStream_t stream)
{
    const float* particles   = (const float*)d_in[0];
    const float* samples     = (const float*)d_in[1];
    const float* weights     = (const float*)d_in[2];
    const float* log_weights = (const float*)d_in[3];
    const float* A           = (const float*)d_in[4];
    const float* B           = (const float*)d_in[5];
    const float* log_sigma   = (const float*)d_in[6];

    const int P = in_sizes[2];  // weights is (P,)

    // layout: jdata P*8 | msoa 4*P | part1 NJ*P | part2 NJ*P
    float* jdata = (float*)d_ws;
    float* msoa  = jdata + (size_t)P * 8;
    float* partbase = msoa + (size_t)P * 4;

    // pick JCHUNK/NJ deterministically to fit ws
    size_t base_bytes = (size_t)P * 12 * sizeof(float);
    int JCHUNK = 32;
    int NJ = P / JCHUNK;
    while (JCHUNK < 128 &&
           base_bytes + (size_t)2 * NJ * P * sizeof(float) > ws_size) {
        JCHUNK <<= 1;
        NJ = P / JCHUNK;
    }
    float* part1 = partbase;
    float* part2 = part1 + (size_t)NJ * P;

    precompute_kernel<<<(P + 255) / 256, 256, 0, stream>>>(
        particles, samples, weights, log_weights, A, B, log_sigma,
        jdata, msoa, P);

    constexpr int R2 = 4, BLOCK = 256;           // 2048 rows / block
    dim3 grid(NJ, P / (2 * R2 * BLOCK));
    switch (JCHUNK) {
    case 32:
        pair_kernel<R2, BLOCK, 32><<<grid, BLOCK, 0, stream>>>(
            jdata, msoa, part1, part2, P);
        break;
    case 64:
        pair_kernel<R2, BLOCK, 64><<<grid, BLOCK, 0, stream>>>(
            jdata, msoa, part1, part2, P);
        break;
    default:
        pair_kernel<R2, BLOCK, 128><<<grid, BLOCK, 0, stream>>>(
            jdata, msoa, part1, part2, P);
        break;
    }

    reduce_kernel<<<P / 64, 256, 0, stream>>>(part1, part2, (float*)d_out, P, NJ);
}